// Round 1
// baseline (5095.727 us; speedup 1.0000x reference)
//
#include <hip/hip_runtime.h>
#include <math.h>

#define B_ 8192
#define L_ 49
#define C_ 512
#define R_ 128

__device__ __forceinline__ float star_relu(float x, float sc, float bi) {
    float r = fmaxf(x, 0.f);
    return sc * r * r + bi;
}
__device__ __forceinline__ float sigmoidf_(float x) {
    return 1.f / (1.f + __expf(-x));
}

// One workgroup per batch element. Entire per-batch pipeline in LDS.
// LDS budget: 100352(sx) + 25088(s_xl) + 25088(s_y) + 4096(max/avg)
//            + 1536(g1/g2/h) + 2048(s_ca) + 256(s_sp) = 158464 B <= 163840.
__global__ __launch_bounds__(256, 1)
void mafn_fused(const float* __restrict__ x,
                const float* __restrict__ g_w,   // (128,512)
                const float* __restrict__ l_w,   // (128,512)
                const float* __restrict__ w3,    // (64,64,3,3)
                const float* __restrict__ b3,    // (64)
                const float* __restrict__ w5,    // (64,64,5,5)
                const float* __restrict__ b5,    // (64)
                const float* __restrict__ cw,    // (512,128)
                const float* __restrict__ cb,    // (512)
                const float* __restrict__ sw,    // (1,384)
                const float* __restrict__ sb,    // (1)
                const float* __restrict__ ssc,   // (1)
                const float* __restrict__ sbi,   // (1)
                float* __restrict__ out)
{
    __shared__ __align__(16) float sx[L_ * C_];     // [l][c]
    __shared__ __align__(16) float s_xl[L_ * R_];   // [l][r]
    __shared__ __align__(16) float s_y[L_ * R_];    // [l][o]
    __shared__ __align__(16) float s_max[C_];
    __shared__ __align__(16) float s_avg[C_];
    __shared__ __align__(16) float s_g1[R_];
    __shared__ __align__(16) float s_g2[R_];
    __shared__ __align__(16) float s_h[R_];
    __shared__ __align__(16) float s_ca[C_];
    __shared__ __align__(16) float s_sp[64];

    const int b = blockIdx.x;
    const int t = threadIdx.x;
    const float scale = ssc[0], sbias = sbi[0];

    // ---- Phase 1: load x[b] (float4 coalesced) ----
    const float4* x4 = reinterpret_cast<const float4*>(x + (size_t)b * (L_ * C_));
    float4* sx4 = reinterpret_cast<float4*>(sx);
    for (int i = t; i < L_ * C_ / 4; i += 256) sx4[i] = x4[i];
    __syncthreads();

    // ---- Phase 2: per-channel max / mean over L ----
    for (int c = t; c < C_; c += 256) {
        float m = -INFINITY, s = 0.f;
        for (int l = 0; l < L_; ++l) {
            float v = sx[l * C_ + c];
            m = fmaxf(m, v);
            s += v;
        }
        s_max[c] = m;
        s_avg[c] = s * (1.f / 49.f);
    }
    __syncthreads();

    // ---- Phase 3: g1 = star_relu(x_max @ g_w^T), g2 = star_relu(x_avg @ g_w^T) ----
    {
        const int which = t >> 7, r = t & 127;
        const float* src = which ? s_avg : s_max;
        const float4* w4 = reinterpret_cast<const float4*>(g_w + r * C_);
        float acc = 0.f;
        for (int c4 = 0; c4 < C_ / 4; ++c4) {
            float4 w = w4[c4];
            const float* sv = src + c4 * 4;
            acc += w.x * sv[0] + w.y * sv[1] + w.z * sv[2] + w.w * sv[3];
        }
        float g = star_relu(acc, scale, sbias);
        if (which == 0) s_g1[r] = g; else s_g2[r] = g;
    }
    __syncthreads();
    if (t < R_) s_h[t] = s_g1[t] + s_g2[t];   // consumed after next barrier

    // ---- Phase 4: x_l[l][r] = sum_c x[l][c] * l_w[r][c] ----
    {
        const int r = t & 127, lh = t >> 7;
        const int lstart = lh * 24;            // groups overlap at l=24 (benign identical write)
        float acc[25];
        #pragma unroll
        for (int i = 0; i < 25; ++i) acc[i] = 0.f;
        const float4* w4 = reinterpret_cast<const float4*>(l_w + r * C_);
        for (int c4 = 0; c4 < C_ / 4; ++c4) {
            float4 w = w4[c4];
            #pragma unroll
            for (int li = 0; li < 25; ++li) {
                float4 xv = sx4[(lstart + li) * (C_ / 4) + c4];   // LDS broadcast
                acc[li] += w.x * xv.x + w.y * xv.y + w.z * xv.z + w.w * xv.w;
            }
        }
        #pragma unroll
        for (int li = 0; li < 25; ++li) s_xl[(lstart + li) * R_ + r] = acc[li];
    }
    __syncthreads();

    // ---- Phase 5: convs. t<128: conv5 (oc=t&63, ic-half h), t>=128: conv3 ----
    {
        float acc[49];
        #pragma unroll
        for (int l = 0; l < 49; ++l) acc[l] = 0.f;
        float xcol[49];

        if (t < 128) {
            const int oc = t & 63, h = t >> 6;
            const float* wrow = w5 + (oc * 64 + h * 32) * 25;
            for (int ic = 0; ic < 32; ++ic) {
                #pragma unroll
                for (int l = 0; l < 49; ++l) xcol[l] = s_xl[l * R_ + 64 + h * 32 + ic];
                const float* wp = wrow + ic * 25;
                #pragma unroll
                for (int ki = 0; ki < 5; ++ki) {
                    #pragma unroll
                    for (int kj = 0; kj < 5; ++kj) {
                        float w = wp[ki * 5 + kj];
                        #pragma unroll
                        for (int i = 0; i < 7; ++i) {
                            int ii = i + ki - 2;
                            if (ii < 0 || ii > 6) continue;           // compile-time
                            #pragma unroll
                            for (int j = 0; j < 7; ++j) {
                                int jj = j + kj - 2;
                                if (jj < 0 || jj > 6) continue;       // compile-time
                                acc[i * 7 + j] += w * xcol[ii * 7 + jj];
                            }
                        }
                    }
                }
            }
        } else {
            const int o = t & 63, h = (t >> 6) & 1;
            const float* wrow = w3 + (o * 64 + h * 32) * 9;
            for (int ic = 0; ic < 32; ++ic) {
                #pragma unroll
                for (int l = 0; l < 49; ++l) xcol[l] = s_xl[l * R_ + h * 32 + ic];
                const float* wp = wrow + ic * 9;
                #pragma unroll
                for (int ki = 0; ki < 3; ++ki) {
                    #pragma unroll
                    for (int kj = 0; kj < 3; ++kj) {
                        float w = wp[ki * 3 + kj];
                        #pragma unroll
                        for (int i = 0; i < 7; ++i) {
                            int ii = i + ki - 1;
                            if (ii < 0 || ii > 6) continue;
                            #pragma unroll
                            for (int j = 0; j < 7; ++j) {
                                int jj = j + kj - 1;
                                if (jj < 0 || jj > 6) continue;
                                acc[i * 7 + j] += w * xcol[ii * 7 + jj];
                            }
                        }
                    }
                }
            }
        }

        const int ocat = (t < 128) ? (64 + (t & 63)) : (t & 63);
        const int h = (t >> 6) & 1;
        if (h == 0) {
            #pragma unroll
            for (int l = 0; l < 49; ++l) s_y[l * R_ + ocat] = acc[l];
        }
        __syncthreads();
        if (h == 1) {
            #pragma unroll
            for (int l = 0; l < 49; ++l) s_y[l * R_ + ocat] += acc[l];
        }
        __syncthreads();
    }

    // ---- Phase 6: bias + star_relu on conv output ----
    if (t < 128) {
        const float bias = (t < 64) ? b3[t] : b5[t - 64];
        #pragma unroll
        for (int l = 0; l < 49; ++l)
            s_y[l * R_ + t] = star_relu(s_y[l * R_ + t] + bias, scale, sbias);
    }
    __syncthreads();

    // ---- Phase 7a: c_aggr[c] = sigmoid((g1+g2)@cw^T + 2*cb) ----
    for (int c = t; c < C_; c += 256) {
        const float4* cw4 = reinterpret_cast<const float4*>(cw + c * R_);
        float acc = 0.f;
        for (int r4 = 0; r4 < R_ / 4; ++r4) {
            float4 w = cw4[r4];
            const float* hp = s_h + r4 * 4;
            acc += w.x * hp[0] + w.y * hp[1] + w.z * hp[2] + w.w * hp[3];
        }
        s_ca[c] = sigmoidf_(acc + 2.f * cb[c]);
    }
    // ---- Phase 7b: spatial gate per l ----
    if (t < 49) {
        float acc = sb[0];
        for (int o = 0; o < 128; ++o) acc += s_y[t * R_ + o] * sw[o];
        for (int r = 0; r < 128; ++r) acc += s_g1[r] * sw[128 + r] + s_g2[r] * sw[256 + r];
        s_sp[t] = sigmoidf_(acc);
    }
    __syncthreads();

    // ---- Phase 8: out = x * c_aggr[c] * s_aggr[l] ----
    float4* out4 = reinterpret_cast<float4*>(out + (size_t)b * (L_ * C_));
    const float4* ca4 = reinterpret_cast<const float4*>(s_ca);
    for (int i = t; i < L_ * C_ / 4; i += 256) {
        int l = i >> 7;      // 128 float4 per row
        int c4 = i & 127;
        float4 xv = sx4[i];
        float sa = s_sp[l];
        float4 cav = ca4[c4];
        float4 ov;
        ov.x = xv.x * cav.x * sa;
        ov.y = xv.y * cav.y * sa;
        ov.z = xv.z * cav.z * sa;
        ov.w = xv.w * cav.w * sa;
        out4[i] = ov;
    }
}

extern "C" void kernel_launch(void* const* d_in, const int* in_sizes, int n_in,
                              void* d_out, int out_size, void* d_ws, size_t ws_size,
                              hipStream_t stream) {
    (void)in_sizes; (void)n_in; (void)d_ws; (void)ws_size; (void)out_size;
    const float* x    = (const float*)d_in[0];
    const float* g_w  = (const float*)d_in[1];
    const float* l_w  = (const float*)d_in[2];
    const float* w3   = (const float*)d_in[3];
    const float* b3   = (const float*)d_in[4];
    const float* w5   = (const float*)d_in[5];
    const float* b5   = (const float*)d_in[6];
    const float* cw   = (const float*)d_in[7];
    const float* cb   = (const float*)d_in[8];
    const float* sw   = (const float*)d_in[9];
    const float* sb   = (const float*)d_in[10];
    const float* ssc  = (const float*)d_in[11];
    const float* sbi  = (const float*)d_in[12];
    float* outp = (float*)d_out;

    mafn_fused<<<dim3(B_), dim3(256), 0, stream>>>(
        x, g_w, l_w, w3, b3, w5, b5, cw, cb, sw, sb, ssc, sbi, outp);
}

// Round 2
// 1365.819 us; speedup vs baseline: 3.7309x; 3.7309x over previous
//
#include <hip/hip_runtime.h>
#include <math.h>

#define B_ 8192
#define L_ 49
#define C_ 512
#define R_ 128

typedef short   bf16x8 __attribute__((ext_vector_type(8)));
typedef unsigned short u16x8 __attribute__((ext_vector_type(8)));
typedef float   f32x4  __attribute__((ext_vector_type(4)));

// ws layout (ushort elements)
#define WS_LWB   0           // [128][512]  l_reduce_w bf16
#define WS_WB3   65536       // [9][64][64] w3 tap-major bf16
#define WS_WB5   102400      // [25][64][64] w5 tap-major bf16  (65536+36864)
#define WS_GWB   204800      // [128][512]  g_reduce_w bf16     (102400+102400)
#define WS_CWB   270336      // [512][128]  channel_w bf16      (204800+65536)
#define WS_TOT   335872

__device__ __forceinline__ float bf2f(unsigned short u) {
    union { float f; unsigned int i; } v; v.i = ((unsigned int)u) << 16; return v.f;
}
__device__ __forceinline__ unsigned short f2bf(float f) {
    union { float f; unsigned int i; } v; v.f = f;
    unsigned int r = v.i + 0x7fffu + ((v.i >> 16) & 1u);
    return (unsigned short)(r >> 16);
}
__device__ __forceinline__ float star_relu(float x, float sc, float bi) {
    float r = fmaxf(x, 0.f);
    return sc * r * r + bi;
}
__device__ __forceinline__ float sigmoidf_(float x) {
    return 1.f / (1.f + __expf(-x));
}

// ---------------- pre-pass: convert weights to bf16 into ws ----------------
__global__ void cvt_weights(const float* __restrict__ lw, const float* __restrict__ w3,
                            const float* __restrict__ w5, const float* __restrict__ gw,
                            const float* __restrict__ cw, unsigned short* __restrict__ ws)
{
    int t = blockIdx.x * blockDim.x + threadIdx.x;
    int stride = gridDim.x * blockDim.x;
    for (int i = t; i < 65536; i += stride) ws[WS_LWB + i] = f2bf(lw[i]);
    for (int i = t; i < 65536; i += stride) ws[WS_GWB + i] = f2bf(gw[i]);
    for (int i = t; i < 65536; i += stride) ws[WS_CWB + i] = f2bf(cw[i]);
    for (int i = t; i < 36864; i += stride) {             // [tap][o][ic] <- w3[o][ic][tap]
        int tap = i >> 12, rem = i & 4095;
        ws[WS_WB3 + i] = f2bf(w3[rem * 9 + tap]);
    }
    for (int i = t; i < 102400; i += stride) {            // [tap][o][ic] <- w5[o][ic][tap]
        int tap = i / 4096, rem = i % 4096;
        ws[WS_WB5 + i] = f2bf(w5[rem * 25 + tap]);
    }
}

// ---------------- conv tap-GEMM body (compile-time constants) ----------------
template <int NTAP, int KD, int PAD, int COLBASE>
__device__ __forceinline__ void conv_mfma(const unsigned short* __restrict__ s_xlb,
                                          const unsigned short* __restrict__ wtb,
                                          int m16, int kg, int oc, f32x4 C[4])
{
    const bf16x8 zz = {0,0,0,0,0,0,0,0};
    #pragma unroll
    for (int tap = 0; tap < NTAP; ++tap) {
        const int dy = tap / KD - PAD, dx = tap % KD - PAD;
        int lc[4]; bool vld[4];
        #pragma unroll
        for (int mf = 0; mf < 4; ++mf) {
            int lp = mf * 16 + m16;
            int i = lp / 7, j = lp % 7;
            int ii = i + dy, jj = j + dx;
            vld[mf] = (lp < 49) && (ii >= 0) && (ii < 7) && (jj >= 0) && (jj < 7);
            int ls = lp + dy * 7 + dx;
            lc[mf] = min(max(ls, 0), 63);
        }
        #pragma unroll
        for (int ks = 0; ks < 2; ++ks) {
            bf16x8 bb = *(const bf16x8*)(wtb + tap * 4096 + oc * 64 + ks * 32 + kg * 8);
            #pragma unroll
            for (int mf = 0; mf < 4; ++mf) {
                bf16x8 a = *(const bf16x8*)&s_xlb[lc[mf] * 136 + COLBASE + ks * 32 + kg * 8];
                if (!vld[mf]) a = zz;
                C[mf] = __builtin_amdgcn_mfma_f32_16x16x32_bf16(a, bb, C[mf], 0, 0, 0);
            }
        }
    }
}

// ---------------- main fused kernel: one block per batch ----------------
__global__ __launch_bounds__(512)
void mafn_fused(const float* __restrict__ x,
                const float* __restrict__ b3, const float* __restrict__ b5,
                const float* __restrict__ cb, const float* __restrict__ sw,
                const float* __restrict__ sb, const float* __restrict__ ssc,
                const float* __restrict__ sbi,
                const unsigned short* __restrict__ ws,
                float* __restrict__ out)
{
    __shared__ __align__(16) unsigned short s_xb[64 * 520];   // x bf16, padded stride
    __shared__ __align__(16) unsigned short s_xlb[64 * 136];  // x_l bf16, padded stride
    __shared__ __align__(16) float s_red[2][4][512];
    __shared__ __align__(16) float s_max[512];
    __shared__ __align__(16) float s_avg[512];
    __shared__ __align__(16) float s_g[2][128];
    __shared__ __align__(16) float s_ca[512];
    __shared__ float s_spacc[64];
    __shared__ float s_sp[64];
    __shared__ float s_gdot;

    const int b = blockIdx.x, t = threadIdx.x;
    const int wv = t >> 6, ln = t & 63;
    const int m16 = ln & 15, kg = ln >> 4;
    const float scale = ssc[0], sbias = sbi[0];

    const unsigned short* lwb = ws + WS_LWB;
    const unsigned short* wb3 = ws + WS_WB3;
    const unsigned short* wb5 = ws + WS_WB5;
    const unsigned short* gwb = ws + WS_GWB;
    const unsigned short* cwb = ws + WS_CWB;

    // ---- P1: load x (f32), exact max/sum partials, convert to bf16 LDS ----
    {
        const float4* x4 = (const float4*)(x + (size_t)b * (L_ * C_));
        const int c4 = t & 127, lg = t >> 7;
        const int l0 = lg * 12;
        const int nl = (lg < 3) ? 12 : 13;
        float4 mx = {-3.4e38f, -3.4e38f, -3.4e38f, -3.4e38f};
        float4 sm = {0.f, 0.f, 0.f, 0.f};
        for (int li = 0; li < nl; ++li) {
            int l = l0 + li;
            float4 v = x4[l * 128 + c4];
            mx.x = fmaxf(mx.x, v.x); mx.y = fmaxf(mx.y, v.y);
            mx.z = fmaxf(mx.z, v.z); mx.w = fmaxf(mx.w, v.w);
            sm.x += v.x; sm.y += v.y; sm.z += v.z; sm.w += v.w;
            ushort4 p;
            p.x = f2bf(v.x); p.y = f2bf(v.y); p.z = f2bf(v.z); p.w = f2bf(v.w);
            *(ushort4*)&s_xb[l * 520 + c4 * 4] = p;
        }
        *(float4*)&s_red[0][lg][c4 * 4] = mx;
        *(float4*)&s_red[1][lg][c4 * 4] = sm;
    }
    __syncthreads();

    // ---- P2: finalize max/avg; init accumulators ----
    {
        int c = t;
        float m = fmaxf(fmaxf(s_red[0][0][c], s_red[0][1][c]),
                        fmaxf(s_red[0][2][c], s_red[0][3][c]));
        float s = s_red[1][0][c] + s_red[1][1][c] + s_red[1][2][c] + s_red[1][3][c];
        s_max[c] = m;
        s_avg[c] = s * (1.f / 49.f);
        if (t < 64) s_spacc[t] = 0.f;
    }
    __syncthreads();

    // ---- P3: waves 0-3: x_l GEMM (MFMA)  ||  waves 4-7: g-GEMM (f32) ----
    f32x4 accA[4][2];
    if (wv < 4) {
        const f32x4 z = {0.f, 0.f, 0.f, 0.f};
        #pragma unroll
        for (int mf = 0; mf < 4; ++mf) { accA[mf][0] = z; accA[mf][1] = z; }
        const int wn = wv;
        #pragma unroll 4
        for (int ks = 0; ks < 16; ++ks) {
            bf16x8 a[4];
            #pragma unroll
            for (int mf = 0; mf < 4; ++mf)
                a[mf] = *(const bf16x8*)&s_xb[(mf * 16 + m16) * 520 + ks * 32 + kg * 8];
            #pragma unroll
            for (int bf = 0; bf < 2; ++bf) {
                int n = wn * 32 + bf * 16 + m16;
                bf16x8 bb = *(const bf16x8*)(lwb + n * 512 + ks * 32 + kg * 8);
                #pragma unroll
                for (int mf = 0; mf < 4; ++mf)
                    accA[mf][bf] = __builtin_amdgcn_mfma_f32_16x16x32_bf16(a[mf], bb, accA[mf][bf], 0, 0, 0);
            }
        }
    } else {
        const int idx = t - 256, which = idx >> 7, r = idx & 127;
        const float4* s4 = (const float4*)(which ? s_avg : s_max);
        const unsigned short* wrow = gwb + r * 512;
        float acc = 0.f;
        #pragma unroll 4
        for (int c8 = 0; c8 < 64; ++c8) {
            u16x8 w = *(const u16x8*)(wrow + c8 * 8);
            float4 v0 = s4[c8 * 2], v1 = s4[c8 * 2 + 1];
            acc += bf2f(w[0]) * v0.x + bf2f(w[1]) * v0.y + bf2f(w[2]) * v0.z + bf2f(w[3]) * v0.w
                 + bf2f(w[4]) * v1.x + bf2f(w[5]) * v1.y + bf2f(w[6]) * v1.z + bf2f(w[7]) * v1.w;
        }
        s_g[which][r] = star_relu(acc, scale, sbias);
    }
    __syncthreads();

    // ---- P4: waves 0-3: store x_l bf16  ||  waves 4-7: c_aggr + gdot ----
    if (wv < 4) {
        const int wn = wv;
        #pragma unroll
        for (int mf = 0; mf < 4; ++mf) {
            #pragma unroll
            for (int bf = 0; bf < 2; ++bf) {
                int n = wn * 32 + bf * 16 + m16;
                #pragma unroll
                for (int rg = 0; rg < 4; ++rg) {
                    int lp = mf * 16 + kg * 4 + rg;
                    s_xlb[lp * 136 + n] = f2bf(accA[mf][bf][rg]);
                }
            }
        }
    } else {
        const int idx = t - 256;
        #pragma unroll
        for (int half = 0; half < 2; ++half) {
            int c = idx + half * 256;
            const unsigned short* wrow = cwb + c * 128;
            float acc = 0.f;
            #pragma unroll 2
            for (int r8 = 0; r8 < 16; ++r8) {
                u16x8 w = *(const u16x8*)(wrow + r8 * 8);
                #pragma unroll
                for (int k = 0; k < 8; ++k) {
                    int r = r8 * 8 + k;
                    acc += bf2f(w[k]) * (s_g[0][r] + s_g[1][r]);
                }
            }
            s_ca[c] = sigmoidf_(acc + 2.f * cb[c]);
        }
        if (wv == 7) {
            float p = s_g[0][ln] * sw[128 + ln] + s_g[1][ln] * sw[256 + ln]
                    + s_g[0][ln + 64] * sw[128 + ln + 64] + s_g[1][ln + 64] * sw[256 + ln + 64];
            #pragma unroll
            for (int off = 32; off > 0; off >>= 1) p += __shfl_xor(p, off);
            if (ln == 0) s_gdot = p;
        }
    }
    __syncthreads();

    // ---- P5: convs as masked tap-GEMMs; fuse star_relu + sw-dot epilogue ----
    {
        const bool is5 = (wv < 4);
        const int nf = is5 ? wv : wv - 4;
        const int oc = nf * 16 + m16;            // 0..63 within this conv
        f32x4 C[4];
        const f32x4 z = {0.f, 0.f, 0.f, 0.f};
        #pragma unroll
        for (int mf = 0; mf < 4; ++mf) C[mf] = z;

        if (is5) conv_mfma<25, 5, 2, 64>(s_xlb, wb5, m16, kg, oc, C);
        else     conv_mfma< 9, 3, 1,  0>(s_xlb, wb3, m16, kg, oc, C);

        const int ch = is5 ? 64 + oc : oc;       // concat channel
        const float bias = is5 ? b5[oc] : b3[oc];
        const float sww = sw[ch];
        #pragma unroll
        for (int mf = 0; mf < 4; ++mf) {
            #pragma unroll
            for (int rg = 0; rg < 4; ++rg) {
                int lp = mf * 16 + kg * 4 + rg;
                float v = (lp < 49) ? star_relu(C[mf][rg] + bias, scale, sbias) * sww : 0.f;
                v += __shfl_xor(v, 1);
                v += __shfl_xor(v, 2);
                v += __shfl_xor(v, 4);
                v += __shfl_xor(v, 8);
                if (m16 == 0 && lp < 49) atomicAdd(&s_spacc[lp], v);
            }
        }
    }
    __syncthreads();

    // ---- P6: spatial gate ----
    if (t < 49) s_sp[t] = sigmoidf_(s_spacc[t] + s_gdot + sb[0]);
    __syncthreads();

    // ---- P7: out = x * ca[c] * sp[l] (x re-read f32, L2-hot) ----
    {
        const float4* x4 = (const float4*)(x + (size_t)b * (L_ * C_));
        float4* o4 = (float4*)(out + (size_t)b * (L_ * C_));
        const float4* ca4 = (const float4*)s_ca;
        for (int i = t; i < 49 * 128; i += 512) {
            int l = i >> 7, c4 = i & 127;
            float4 xv = x4[i];
            float g = s_sp[l];
            float4 cv = ca4[c4];
            float4 ov;
            ov.x = xv.x * cv.x * g;
            ov.y = xv.y * cv.y * g;
            ov.z = xv.z * cv.z * g;
            ov.w = xv.w * cv.w * g;
            o4[i] = ov;
        }
    }
}

extern "C" void kernel_launch(void* const* d_in, const int* in_sizes, int n_in,
                              void* d_out, int out_size, void* d_ws, size_t ws_size,
                              hipStream_t stream) {
    (void)in_sizes; (void)n_in; (void)ws_size; (void)out_size;
    const float* x    = (const float*)d_in[0];
    const float* g_w  = (const float*)d_in[1];
    const float* l_w  = (const float*)d_in[2];
    const float* w3   = (const float*)d_in[3];
    const float* b3   = (const float*)d_in[4];
    const float* w5   = (const float*)d_in[5];
    const float* b5   = (const float*)d_in[6];
    const float* cw   = (const float*)d_in[7];
    const float* cb   = (const float*)d_in[8];
    const float* sw   = (const float*)d_in[9];
    const float* sb   = (const float*)d_in[10];
    const float* ssc  = (const float*)d_in[11];
    const float* sbi  = (const float*)d_in[12];
    float* outp = (float*)d_out;
    unsigned short* ws = (unsigned short*)d_ws;

    cvt_weights<<<dim3(512), dim3(256), 0, stream>>>(l_w, w3, w5, g_w, cw, ws);
    mafn_fused<<<dim3(B_), dim3(512), 0, stream>>>(
        x, b3, b5, cb, sw, sb, ssc, sbi, ws, outp);
}

// Round 3
// 975.256 us; speedup vs baseline: 5.2250x; 1.4005x over previous
//
#include <hip/hip_runtime.h>
#include <math.h>

#define B_ 8192
#define L_ 49
#define C_ 512
#define R_ 128

typedef short   bf16x8 __attribute__((ext_vector_type(8)));
typedef unsigned short u16x8 __attribute__((ext_vector_type(8)));
typedef float   f32x4  __attribute__((ext_vector_type(4)));

// ws layout (ushort elements)
#define WS_LWB   0           // [128][512]  l_reduce_w bf16
#define WS_WB3   65536       // [9][64][64] w3 tap-major bf16
#define WS_WB5   102400      // [25][64][64] w5 tap-major bf16
#define WS_GWB   204800      // [128][512]  g_reduce_w bf16
#define WS_CWB   270336      // [512][128]  channel_w bf16

// shared memory layout (bytes)
#define SM_XB    0           // ushort xb[49][512] swizzled   (50176 B)  | after P3: float part[49][65]
#define SM_XLB   50176       // ushort xlb[50][128] swizzled  (12800 B)  | P1-P2: float red[2][4][512] (16384 B)
#define SM_MAX   66560       // float[512]
#define SM_AVG   68608       // float[512]
#define SM_G     70656       // float[2][128]
#define SM_CA    71680       // float[512]
#define SM_SPACC 73728       // float[64]
#define SM_SP    73984       // float[64]
#define SM_GDOT  74240       // float
#define SM_TOT   74256

__device__ __forceinline__ float bf2f(unsigned short u) {
    union { float f; unsigned int i; } v; v.i = ((unsigned int)u) << 16; return v.f;
}
__device__ __forceinline__ unsigned short f2bf(float f) {
    union { float f; unsigned int i; } v; v.f = f;
    unsigned int r = v.i + 0x7fffu + ((v.i >> 16) & 1u);
    return (unsigned short)(r >> 16);
}
__device__ __forceinline__ float star_relu(float x, float sc, float bi) {
    float r = fmaxf(x, 0.f);
    return sc * r * r + bi;
}
__device__ __forceinline__ float sigmoidf_(float x) {
    return 1.f / (1.f + __expf(-x));
}

// ---------------- pre-pass: convert weights to bf16 into ws ----------------
__global__ void cvt_weights(const float* __restrict__ lw, const float* __restrict__ w3,
                            const float* __restrict__ w5, const float* __restrict__ gw,
                            const float* __restrict__ cw, unsigned short* __restrict__ ws)
{
    int t = blockIdx.x * blockDim.x + threadIdx.x;
    int stride = gridDim.x * blockDim.x;
    for (int i = t; i < 65536; i += stride) ws[WS_LWB + i] = f2bf(lw[i]);
    for (int i = t; i < 65536; i += stride) ws[WS_GWB + i] = f2bf(gw[i]);
    for (int i = t; i < 65536; i += stride) ws[WS_CWB + i] = f2bf(cw[i]);
    for (int i = t; i < 36864; i += stride) {             // [tap][o][ic] <- w3[o][ic][tap]
        int tap = i >> 12, rem = i & 4095;
        ws[WS_WB3 + i] = f2bf(w3[rem * 9 + tap]);
    }
    for (int i = t; i < 102400; i += stride) {            // [tap][o][ic] <- w5[o][ic][tap]
        int tap = i / 4096, rem = i % 4096;
        ws[WS_WB5 + i] = f2bf(w5[rem * 25 + tap]);
    }
}

// ---------------- conv tap-GEMM body. Invalid taps read zeroed row 49. ----------------
template <int NTAP, int KD, int PAD, int COLBASE, int T0, int T1>
__device__ __forceinline__ void conv_mfma(const unsigned short* __restrict__ s_xlb,
                                          const unsigned short* __restrict__ wtb,
                                          int m16, int kg, int oc, f32x4 C[4])
{
    int lp_[4], i_[4], j_[4];
    #pragma unroll
    for (int mf = 0; mf < 4; ++mf) {
        lp_[mf] = mf * 16 + m16;
        i_[mf] = lp_[mf] / 7;
        j_[mf] = lp_[mf] % 7;
    }
    #pragma unroll
    for (int tap = T0; tap < T1; ++tap) {
        const int dy = tap / KD - PAD, dx = tap % KD - PAD;
        int lc[4];
        #pragma unroll
        for (int mf = 0; mf < 4; ++mf) {
            int ii = i_[mf] + dy, jj = j_[mf] + dx;
            bool v = (lp_[mf] < 49) & (ii >= 0) & (ii < 7) & (jj >= 0) & (jj < 7);
            lc[mf] = v ? (ii * 7 + jj) : 49;              // row 49 is all zeros
        }
        #pragma unroll
        for (int ks = 0; ks < 2; ++ks) {
            bf16x8 bb = *(const bf16x8*)(wtb + tap * 4096 + oc * 64 + ks * 32 + kg * 8);
            #pragma unroll
            for (int mf = 0; mf < 4; ++mf) {
                int chunk = ((COLBASE >> 3) + ks * 4 + kg) ^ (lc[mf] & 7);
                bf16x8 a = *(const bf16x8*)&s_xlb[lc[mf] * 128 + chunk * 8];
                C[mf] = __builtin_amdgcn_mfma_f32_16x16x32_bf16(a, bb, C[mf], 0, 0, 0);
            }
        }
    }
}

// ---------------- main fused kernel: one block per batch, 2 blocks/CU ----------------
__global__ __launch_bounds__(512, 4)
void mafn_fused(const float* __restrict__ x,
                const float* __restrict__ b3, const float* __restrict__ b5,
                const float* __restrict__ cb, const float* __restrict__ sw,
                const float* __restrict__ sb, const float* __restrict__ ssc,
                const float* __restrict__ sbi,
                const unsigned short* __restrict__ ws,
                float* __restrict__ out)
{
    __shared__ __align__(16) unsigned char smem[SM_TOT];
    unsigned short* s_xb   = (unsigned short*)(smem + SM_XB);   // [49][512] swizzled
    float*          s_part = (float*)(smem + SM_XB);            // [49][65] (overlay, P5)
    unsigned short* s_xlb  = (unsigned short*)(smem + SM_XLB);  // [50][128] swizzled
    float*          s_red  = (float*)(smem + SM_XLB);           // [2][4][512] (overlay, P1-P2)
    float*          s_maxv = (float*)(smem + SM_MAX);
    float*          s_avg  = (float*)(smem + SM_AVG);
    float*          s_g    = (float*)(smem + SM_G);             // [2][128]
    float*          s_ca   = (float*)(smem + SM_CA);
    float*          s_spacc= (float*)(smem + SM_SPACC);
    float*          s_sp   = (float*)(smem + SM_SP);
    float*          s_gdot = (float*)(smem + SM_GDOT);

    const int b = blockIdx.x, t = threadIdx.x;
    const int wv = t >> 6, ln = t & 63;
    const int m16 = ln & 15, kg = ln >> 4;
    const float scale = ssc[0], sbias = sbi[0];

    const unsigned short* lwb = ws + WS_LWB;
    const unsigned short* wb3 = ws + WS_WB3;
    const unsigned short* wb5 = ws + WS_WB5;
    const unsigned short* gwb = ws + WS_GWB;
    const unsigned short* cwb = ws + WS_CWB;

    // ---- P1: load x (f32), exact max/sum partials, bf16 -> swizzled LDS ----
    {
        const float4* x4 = (const float4*)(x + (size_t)b * (L_ * C_));
        const int c4 = t & 127, lg = t >> 7;
        const int l0 = lg * 12;
        const int nl = (lg < 3) ? 12 : 13;
        float4 mx = {-3.4e38f, -3.4e38f, -3.4e38f, -3.4e38f};
        float4 sm = {0.f, 0.f, 0.f, 0.f};
        for (int li = 0; li < nl; ++li) {
            int l = l0 + li;
            float4 v = x4[l * 128 + c4];
            mx.x = fmaxf(mx.x, v.x); mx.y = fmaxf(mx.y, v.y);
            mx.z = fmaxf(mx.z, v.z); mx.w = fmaxf(mx.w, v.w);
            sm.x += v.x; sm.y += v.y; sm.z += v.z; sm.w += v.w;
            ushort4 p;
            p.x = f2bf(v.x); p.y = f2bf(v.y); p.z = f2bf(v.z); p.w = f2bf(v.w);
            int idx = l * 512 + ((((c4 >> 1) ^ (l & 7)) << 3) + (c4 & 1) * 4);
            *(ushort4*)&s_xb[idx] = p;
        }
        *(float4*)&s_red[(0 * 4 + lg) * 512 + c4 * 4] = mx;
        *(float4*)&s_red[(1 * 4 + lg) * 512 + c4 * 4] = sm;
    }
    __syncthreads();

    // ---- P2: finalize max/avg; init spacc ----
    {
        int c = t;
        float m = fmaxf(fmaxf(s_red[0 * 2048 + 0 * 512 + c], s_red[0 * 2048 + 1 * 512 + c]),
                        fmaxf(s_red[0 * 2048 + 2 * 512 + c], s_red[0 * 2048 + 3 * 512 + c]));
        float s = s_red[1 * 2048 + 0 * 512 + c] + s_red[1 * 2048 + 1 * 512 + c]
                + s_red[1 * 2048 + 2 * 512 + c] + s_red[1 * 2048 + 3 * 512 + c];
        s_maxv[c] = m;
        s_avg[c] = s * (1.f / 49.f);
        if (t < 64) s_spacc[t] = 0.f;
    }
    __syncthreads();

    // ---- P3: waves 0-3: x_l GEMM (MFMA)  ||  waves 4-7: g-GEMM (f32) ----
    f32x4 accA[4][2];
    if (wv < 4) {
        const f32x4 z = {0.f, 0.f, 0.f, 0.f};
        int rowA[4];
        #pragma unroll
        for (int mf = 0; mf < 4; ++mf) {
            accA[mf][0] = z; accA[mf][1] = z;
            rowA[mf] = min(mf * 16 + m16, 48);            // clamp; lp>=49 garbage discarded
        }
        const int wn = wv;
        #pragma unroll 4
        for (int ks = 0; ks < 16; ++ks) {
            bf16x8 a[4];
            #pragma unroll
            for (int mf = 0; mf < 4; ++mf) {
                int chunk = (ks * 4 + kg) ^ (rowA[mf] & 7);
                a[mf] = *(const bf16x8*)&s_xb[rowA[mf] * 512 + chunk * 8];
            }
            #pragma unroll
            for (int bf = 0; bf < 2; ++bf) {
                int n = wn * 32 + bf * 16 + m16;
                bf16x8 bb = *(const bf16x8*)(lwb + n * 512 + ks * 32 + kg * 8);
                #pragma unroll
                for (int mf = 0; mf < 4; ++mf)
                    accA[mf][bf] = __builtin_amdgcn_mfma_f32_16x16x32_bf16(a[mf], bb, accA[mf][bf], 0, 0, 0);
            }
        }
    } else {
        const int idx = t - 256, which = idx >> 7, r = idx & 127;
        const float4* s4 = (const float4*)(which ? s_avg : s_maxv);
        const unsigned short* wrow = gwb + r * 512;
        float a0 = 0.f, a1 = 0.f, a2 = 0.f, a3 = 0.f;
        for (int c8 = 0; c8 < 64; c8 += 4) {
            #pragma unroll
            for (int u = 0; u < 4; ++u) {
                u16x8 w = *(const u16x8*)(wrow + (c8 + u) * 8);
                float4 v0 = s4[(c8 + u) * 2], v1 = s4[(c8 + u) * 2 + 1];
                float p = bf2f(w[0]) * v0.x + bf2f(w[1]) * v0.y + bf2f(w[2]) * v0.z + bf2f(w[3]) * v0.w
                        + bf2f(w[4]) * v1.x + bf2f(w[5]) * v1.y + bf2f(w[6]) * v1.z + bf2f(w[7]) * v1.w;
                if (u == 0) a0 += p; else if (u == 1) a1 += p; else if (u == 2) a2 += p; else a3 += p;
            }
        }
        float acc = (a0 + a1) + (a2 + a3);
        s_g[which * 128 + r] = star_relu(acc, scale, sbias);
    }
    __syncthreads();

    // ---- P4: waves 0-3: store x_l bf16 (swizzled) ||  waves 4-7: c_aggr + gdot ----
    if (wv < 4) {
        if (t < 64) ((unsigned int*)(s_xlb + 49 * 128))[t] = 0;   // zero row 49
        const int wn = wv;
        #pragma unroll
        for (int mf = 0; mf < 4; ++mf) {
            #pragma unroll
            for (int bf = 0; bf < 2; ++bf) {
                int n = wn * 32 + bf * 16 + m16;
                #pragma unroll
                for (int rg = 0; rg < 4; ++rg) {
                    int lp = mf * 16 + kg * 4 + rg;
                    if (lp < 49) {
                        int idx = lp * 128 + ((((n >> 3) ^ (lp & 7)) << 3) + (n & 7));
                        s_xlb[idx] = f2bf(accA[mf][bf][rg]);
                    }
                }
            }
        }
    } else {
        const int idx = t - 256;
        #pragma unroll
        for (int half = 0; half < 2; ++half) {
            int c = idx + half * 256;
            const unsigned short* wrow = cwb + c * 128;
            float a0 = 0.f, a1 = 0.f;
            for (int r8 = 0; r8 < 16; r8 += 2) {
                #pragma unroll
                for (int u = 0; u < 2; ++u) {
                    u16x8 w = *(const u16x8*)(wrow + (r8 + u) * 8);
                    float p = 0.f;
                    #pragma unroll
                    for (int k = 0; k < 8; ++k) {
                        int r = (r8 + u) * 8 + k;
                        p += bf2f(w[k]) * (s_g[r] + s_g[128 + r]);
                    }
                    if (u == 0) a0 += p; else a1 += p;
                }
            }
            s_ca[c] = sigmoidf_(a0 + a1 + 2.f * cb[c]);
        }
        if (wv == 7) {
            float p = s_g[ln] * sw[128 + ln] + s_g[128 + ln] * sw[256 + ln]
                    + s_g[ln + 64] * sw[128 + ln + 64] + s_g[128 + ln + 64] * sw[256 + ln + 64];
            #pragma unroll
            for (int off = 32; off > 0; off >>= 1) p += __shfl_xor(p, off);
            if (ln == 0) s_gdot[0] = p;
        }
    }
    __syncthreads();

    // ---- P5a: balanced convs (136 MFMA per wave) ----
    const int f_ = wv & 3;
    const int oc_ = f_ * 16 + m16;
    f32x4 C[4];
    {
        const f32x4 z = {0.f, 0.f, 0.f, 0.f};
        #pragma unroll
        for (int mf = 0; mf < 4; ++mf) C[mf] = z;

        if (wv < 4) {
            conv_mfma<25, 5, 2, 64, 0, 17>(s_xlb, wb5, m16, kg, oc_, C);   // conv5 taps 0..16
        } else {
            f32x4 Cp[4];
            #pragma unroll
            for (int mf = 0; mf < 4; ++mf) Cp[mf] = z;
            conv_mfma<25, 5, 2, 64, 17, 25>(s_xlb, wb5, m16, kg, oc_, Cp); // conv5 taps 17..24
            #pragma unroll
            for (int mf = 0; mf < 4; ++mf) {
                #pragma unroll
                for (int rg = 0; rg < 4; ++rg) {
                    int lp = mf * 16 + kg * 4 + rg;
                    if (lp < 49) s_part[lp * 65 + oc_] = Cp[mf][rg];
                }
            }
            conv_mfma<9, 3, 1, 0, 0, 9>(s_xlb, wb3, m16, kg, oc_, C);      // conv3 full
        }
    }
    __syncthreads();

    // ---- P5b: merge partials; star_relu + sw-dot epilogue ----
    {
        if (wv < 4) {
            #pragma unroll
            for (int mf = 0; mf < 4; ++mf) {
                #pragma unroll
                for (int rg = 0; rg < 4; ++rg) {
                    int lp = mf * 16 + kg * 4 + rg;
                    if (lp < 49) C[mf][rg] += s_part[lp * 65 + oc_];
                }
            }
        }
        const bool is5 = (wv < 4);
        const int ch = is5 ? 64 + oc_ : oc_;
        const float bias = is5 ? b5[oc_] : b3[oc_];
        const float sww = sw[ch];
        #pragma unroll
        for (int mf = 0; mf < 4; ++mf) {
            #pragma unroll
            for (int rg = 0; rg < 4; ++rg) {
                int lp = mf * 16 + kg * 4 + rg;
                float v = (lp < 49) ? star_relu(C[mf][rg] + bias, scale, sbias) * sww : 0.f;
                v += __shfl_xor(v, 1);
                v += __shfl_xor(v, 2);
                v += __shfl_xor(v, 4);
                v += __shfl_xor(v, 8);
                if (m16 == 0 && lp < 49) atomicAdd(&s_spacc[lp], v);
            }
        }
    }
    __syncthreads();

    // ---- P6: spatial gate ----
    if (t < 49) s_sp[t] = sigmoidf_(s_spacc[t] + s_gdot[0] + sb[0]);
    __syncthreads();

    // ---- P7: out = x * ca[c] * sp[l] (x re-read f32, L2-hot) ----
    {
        const float4* x4 = (const float4*)(x + (size_t)b * (L_ * C_));
        float4* o4 = (float4*)(out + (size_t)b * (L_ * C_));
        const float4* ca4 = (const float4*)s_ca;
        for (int i = t; i < 49 * 128; i += 512) {
            int l = i >> 7, c4 = i & 127;
            float4 xv = x4[i];
            float g = s_sp[l];
            float4 cv = ca4[c4];
            float4 ov;
            ov.x = xv.x * cv.x * g;
            ov.y = xv.y * cv.y * g;
            ov.z = xv.z * cv.z * g;
            ov.w = xv.w * cv.w * g;
            o4[i] = ov;
        }
    }
}

extern "C" void kernel_launch(void* const* d_in, const int* in_sizes, int n_in,
                              void* d_out, int out_size, void* d_ws, size_t ws_size,
                              hipStream_t stream) {
    (void)in_sizes; (void)n_in; (void)ws_size; (void)out_size;
    const float* x    = (const float*)d_in[0];
    const float* g_w  = (const float*)d_in[1];
    const float* l_w  = (const float*)d_in[2];
    const float* w3   = (const float*)d_in[3];
    const float* b3   = (const float*)d_in[4];
    const float* w5   = (const float*)d_in[5];
    const float* b5   = (const float*)d_in[6];
    const float* cw   = (const float*)d_in[7];
    const float* cb   = (const float*)d_in[8];
    const float* sw   = (const float*)d_in[9];
    const float* sb   = (const float*)d_in[10];
    const float* ssc  = (const float*)d_in[11];
    const float* sbi  = (const float*)d_in[12];
    float* outp = (float*)d_out;
    unsigned short* ws = (unsigned short*)d_ws;

    cvt_weights<<<dim3(512), dim3(256), 0, stream>>>(l_w, w3, w5, g_w, cw, ws);
    mafn_fused<<<dim3(B_), dim3(512), 0, stream>>>(
        x, b3, b5, cb, sw, sb, ssc, sbi, ws, outp);
}